// Round 1
// baseline (803.749 us; speedup 1.0000x reference)
//
#include <hip/hip_runtime.h>

// Invariant Point Attention (Multimer), B=1, N=768, CS=384, CZ=128, H=12, C=16, PQ=4, PV=8.
// Strategy: fused flash-style attention so the 302MB z tensor is streamed from HBM exactly once.
// K1: s-projections GEMM -> raw qs/ks/v/qp/kp/vp
// K1b: rotate+translate points to global frame, precompute sum_p |qp|^2, |kp|^2
// K2: fused bias(z@Wb) + logits + online softmax + {o, o_pt, o_pair} accumulation, writes cat rows
// K3: cat @ Wout + bout

#define NN 768
#define CSD 384
#define CZD 128
#define HD 12
#define CD 16
#define PQD 4
#define PVD 8

#define TQ 2
#define TK 32
#define ZSTR 132  // z LDS row stride (floats), 16B-aligned rows

// ---------------------------------------------------------------------------
// K1: projections.  grid (48, 9), 256 thr.  16 rows x 128 cols per block.
// col space: [0,192) Wq*0.25 | [192,384) Wk | [384,576) Wv |
//            [576,720) Wqp+bqp | [720,864) Wkp+bkp | [864,1152) Wvp+bvp
// ---------------------------------------------------------------------------
__global__ __launch_bounds__(256) void k1_proj(
    const float* __restrict__ s,
    const float* __restrict__ Wq, const float* __restrict__ Wk, const float* __restrict__ Wv,
    const float* __restrict__ Wqp, const float* __restrict__ bqp,
    const float* __restrict__ Wkp, const float* __restrict__ bkp,
    const float* __restrict__ Wvp, const float* __restrict__ bvp,
    float* __restrict__ qs_w, float* __restrict__ ks_w, float* __restrict__ v_w,
    float* __restrict__ qp_w, float* __restrict__ kp_w, float* __restrict__ vp_w)
{
    __shared__ float s_l[16][CSD];
    const int n0 = blockIdx.x * 16;
    const int t = threadIdx.x;
    for (int i = t; i < 1536; i += 256) {           // 16*384/4 float4s
        int r = i / 96, c4 = i % 96;
        *(float4*)&s_l[r][c4 * 4] = *(const float4*)&s[(size_t)(n0 + r) * CSD + c4 * 4];
    }
    __syncthreads();

    const int jl = t & 127;
    const int rh = t >> 7;                          // 0..1 (wave-uniform)
    const int j = blockIdx.y * 128 + jl;            // 0..1151

    const float* W; const float* bias = nullptr; float* dst;
    int lc, nc, dstride; float scale = 1.0f;
    if (j < 192)      { W = Wq;  lc = j;       nc = 192; dst = qs_w; dstride = 192; scale = 0.25f; }
    else if (j < 384) { W = Wk;  lc = j - 192; nc = 192; dst = ks_w; dstride = 192; }
    else if (j < 576) { W = Wv;  lc = j - 384; nc = 192; dst = v_w;  dstride = 192; }
    else if (j < 720) { W = Wqp; lc = j - 576; nc = 144; dst = qp_w; dstride = 144; bias = bqp; }
    else if (j < 864) { W = Wkp; lc = j - 720; nc = 144; dst = kp_w; dstride = 144; bias = bkp; }
    else              { W = Wvp; lc = j - 864; nc = 288; dst = vp_w; dstride = 288; bias = bvp; }

    float acc[8];
#pragma unroll
    for (int i = 0; i < 8; ++i) acc[i] = 0.f;

    for (int c4 = 0; c4 < 96; ++c4) {
        float w0 = W[(c4 * 4 + 0) * nc + lc];
        float w1 = W[(c4 * 4 + 1) * nc + lc];
        float w2 = W[(c4 * 4 + 2) * nc + lc];
        float w3 = W[(c4 * 4 + 3) * nc + lc];
#pragma unroll
        for (int i = 0; i < 8; ++i) {
            float4 sv = *(const float4*)&s_l[rh + 2 * i][c4 * 4];
            acc[i] += sv.x * w0 + sv.y * w1 + sv.z * w2 + sv.w * w3;
        }
    }
    float b = bias ? bias[lc] : 0.f;
#pragma unroll
    for (int i = 0; i < 8; ++i) {
        int n = n0 + rh + 2 * i;
        dst[(size_t)n * dstride + lc] = acc[i] * scale + b;
    }
}

// ---------------------------------------------------------------------------
// K1b: point transforms to global frame (in-place) + squared-norm sums.
// raw layout per (n,h): [d][P]; transformed: [P][3].  grid 36 x 256 = 9216 = N*H.
// ---------------------------------------------------------------------------
__global__ __launch_bounds__(256) void k1b_points(
    const float* __restrict__ rot, const float* __restrict__ trans,
    float* __restrict__ qp_w, float* __restrict__ kp_w, float* __restrict__ vp_w,
    float* __restrict__ q2s, float* __restrict__ k2s)
{
    int id = blockIdx.x * 256 + threadIdx.x;
    if (id >= NN * HD) return;
    int n = id / HD, h = id % HD;
    float R[9], T[3];
#pragma unroll
    for (int i = 0; i < 9; ++i) R[i] = rot[n * 9 + i];
#pragma unroll
    for (int i = 0; i < 3; ++i) T[i] = trans[n * 3 + i];

    {   // qp (PQ=4)
        float* p = qp_w + (size_t)n * (HD * PQD * 3) + h * (PQD * 3);
        float l[12];
#pragma unroll
        for (int i = 0; i < 12; ++i) l[i] = p[i];
        float s2 = 0.f;
#pragma unroll
        for (int pp = 0; pp < 4; ++pp) {
            float x = l[pp], y = l[4 + pp], z = l[8 + pp];
            float gx = R[0] * x + R[1] * y + R[2] * z + T[0];
            float gy = R[3] * x + R[4] * y + R[5] * z + T[1];
            float gz = R[6] * x + R[7] * y + R[8] * z + T[2];
            p[pp * 3 + 0] = gx; p[pp * 3 + 1] = gy; p[pp * 3 + 2] = gz;
            s2 += gx * gx + gy * gy + gz * gz;
        }
        q2s[n * HD + h] = s2;
    }
    {   // kp (PQ=4)
        float* p = kp_w + (size_t)n * (HD * PQD * 3) + h * (PQD * 3);
        float l[12];
#pragma unroll
        for (int i = 0; i < 12; ++i) l[i] = p[i];
        float s2 = 0.f;
#pragma unroll
        for (int pp = 0; pp < 4; ++pp) {
            float x = l[pp], y = l[4 + pp], z = l[8 + pp];
            float gx = R[0] * x + R[1] * y + R[2] * z + T[0];
            float gy = R[3] * x + R[4] * y + R[5] * z + T[1];
            float gz = R[6] * x + R[7] * y + R[8] * z + T[2];
            p[pp * 3 + 0] = gx; p[pp * 3 + 1] = gy; p[pp * 3 + 2] = gz;
            s2 += gx * gx + gy * gy + gz * gz;
        }
        k2s[n * HD + h] = s2;
    }
    {   // vp (PV=8)
        float* p = vp_w + (size_t)n * (HD * PVD * 3) + h * (PVD * 3);
        float l[24];
#pragma unroll
        for (int i = 0; i < 24; ++i) l[i] = p[i];
#pragma unroll
        for (int pp = 0; pp < 8; ++pp) {
            float x = l[pp], y = l[8 + pp], z = l[16 + pp];
            p[pp * 3 + 0] = R[0] * x + R[1] * y + R[2] * z + T[0];
            p[pp * 3 + 1] = R[3] * x + R[4] * y + R[5] * z + T[1];
            p[pp * 3 + 2] = R[6] * x + R[7] * y + R[8] * z + T[2];
        }
    }
}

// ---------------------------------------------------------------------------
// K2: fused attention.  grid 384 blocks (TQ=2 q-rows each), 256 thr.
// Per k-tile (TK=32): stage z in LDS + compute bias partials from staging regs;
// logits+online softmax by 32-lane groups (24 (q,h) states); accumulate
// o_pair per (q,c) column from LDS, o/o_pt as per-thread float4 from global.
// ---------------------------------------------------------------------------
__global__ __launch_bounds__(256, 2) void k2_attn(
    const float* __restrict__ z, const float* __restrict__ mask,
    const float* __restrict__ rot, const float* __restrict__ trans,
    const float* __restrict__ Wb, const float* __restrict__ bb, const float* __restrict__ hw,
    const float* __restrict__ qs_w, const float* __restrict__ ks_w, const float* __restrict__ v_w,
    const float* __restrict__ qp_w, const float* __restrict__ kp_w, const float* __restrict__ vp_w,
    const float* __restrict__ q2s, const float* __restrict__ k2s,
    float* __restrict__ cat_w)
{
    __shared__ float z_t[TQ * TK * ZSTR];   // [row][132], rows = (q,k)
    __shared__ float p_t[TQ * TK * 16];     // softmax weights, [row][16] (h<12 used)
    __shared__ float wb_l[4 * 392];         // Wb in 4 c-sections of 384 (+8 pad) -> conflict-free
    __shared__ float bias_l[4 * 833];       // bias partials [sec][row*13+h]
    __shared__ float qs_l[TQ * HD * CD];
    __shared__ float qp_l[TQ * HD * 12];
    __shared__ float q2s_l[TQ * HD];
    __shared__ float m_l[TQ * HD], l_l[TQ * HD], sc_l_[TQ * HD];
    __shared__ float bbpw[2 * HD];          // [0..11]=bb, [12..23]=pw
    __shared__ float mq_l[TQ];
    __shared__ float opt_l[TQ * 288];

    const int t = threadIdx.x;
    const int q0 = blockIdx.x * TQ;

    for (int i = t; i < 1536; i += 256) wb_l[(i / 384) * 392 + (i % 384)] = Wb[i];
    for (int i = t; i < TQ * HD * CD; i += 256) qs_l[i] = qs_w[(size_t)q0 * HD * CD + i];
    for (int i = t; i < TQ * HD * 12; i += 256) qp_l[i] = qp_w[(size_t)q0 * HD * 12 + i];
    if (t < TQ * HD) { q2s_l[t] = q2s[q0 * HD + t]; m_l[t] = -1e30f; l_l[t] = 0.f; }
    if (t < HD) {
        bbpw[t] = bb[t];
        bbpw[HD + t] = log1pf(__expf(hw[t])) * 0.23570226039551584f; // softplus * sqrt(2/(9*PQ))
    }
    if (t < TQ) mq_l[t] = mask[q0 + t];

    // accumulators
    float a_pair[12];
#pragma unroll
    for (int h = 0; h < 12; ++h) a_pair[h] = 0.f;
    float4 a_ov; a_ov.x = a_ov.y = a_ov.z = a_ov.w = 0.f;

    // ownership decodes
    const int pr_q = t >> 7, pr_c = t & 127;                  // o_pair (q, c)
    const bool ov_is_o = (t < 96);
    const bool ov_valid = (t < 240);
    int ov_q = 0, ov_h = 0, ov_off = 0;
    if (ov_is_o)      { ov_q = t / 48; int hc = t % 48; ov_h = hc >> 2; ov_off = ov_h * 16 + (hc & 3) * 4; }
    else if (ov_valid){ int u = t - 96; ov_q = u / 72; int r4 = u % 72; ov_h = r4 / 6; ov_off = r4 * 4; }
    const int ld_r = t >> 2, ld_cq = t & 3;                   // loader: row 0..63, c-chunk
    const int ld_q = ld_r >> 5, ld_k = ld_r & 31;
    const int lg_g = t >> 5, lg_kk = t & 31;                  // logits: group, k-in-tile

    const float sqrt3i = 0.57735026918962576f;

    for (int kt = 0; kt < NN / TK; ++kt) {
        const int k0 = kt * TK;
        __syncthreads();   // previous accumulate done (z_t/p_t reusable)

        // ---- stage z tile + bias partials from registers ----
        {
            const float* zsrc = z + ((size_t)(q0 + ld_q) * NN + (k0 + ld_k)) * CZD + ld_cq * 32;
            float4 zr[8];
#pragma unroll
            for (int i = 0; i < 8; ++i) zr[i] = *(const float4*)(zsrc + i * 4);
            float* zdst = &z_t[ld_r * ZSTR + ld_cq * 32];
#pragma unroll
            for (int i = 0; i < 8; ++i) *(float4*)(zdst + i * 4) = zr[i];

            float bacc[12];
#pragma unroll
            for (int h = 0; h < 12; ++h) bacc[h] = 0.f;
            const float* wbs = &wb_l[ld_cq * 392];
#pragma unroll
            for (int i = 0; i < 8; ++i) {
                const float* w0 = wbs + i * 48;
                float4 zv = zr[i];
#pragma unroll
                for (int h = 0; h < 12; ++h)
                    bacc[h] += zv.x * w0[h] + zv.y * w0[12 + h] + zv.z * w0[24 + h] + zv.w * w0[36 + h];
            }
            float* bdst = &bias_l[ld_cq * 833 + ld_r * 13];
#pragma unroll
            for (int h = 0; h < 12; ++h) bdst[h] = bacc[h];
        }
        __syncthreads();

        // ---- logits + online softmax (group = 32 lanes over k; 3 (q,h) reps) ----
        {
            const int kg = k0 + lg_kk;
            const float mk = mask[kg];
#pragma unroll
            for (int rep = 0; rep < 3; ++rep) {
                const int qh = lg_g + rep * 8;
                const int lq = qh / 12, lh = qh % 12;
                const int row = lq * TK + lg_kk;
                float lg = bias_l[row * 13 + lh] + bias_l[833 + row * 13 + lh]
                         + bias_l[1666 + row * 13 + lh] + bias_l[2499 + row * 13 + lh];
                lg += bbpw[lh];
                // scalar q.k
                const float4* ksp = (const float4*)(ks_w + (size_t)kg * 192 + lh * 16);
                const float4* qsp = (const float4*)&qs_l[(lq * 12 + lh) * 16];
                float ss = 0.f;
#pragma unroll
                for (int i = 0; i < 4; ++i) {
                    float4 a = qsp[i], b = ksp[i];
                    ss += a.x * b.x + a.y * b.y + a.z * b.z + a.w * b.w;
                }
                // point distance term
                const float4* kpp = (const float4*)(kp_w + (size_t)kg * 144 + lh * 12);
                const float4* qpp = (const float4*)&qp_l[(lq * 12 + lh) * 12];
                float cr = 0.f;
#pragma unroll
                for (int i = 0; i < 3; ++i) {
                    float4 a = qpp[i], b = kpp[i];
                    cr += a.x * b.x + a.y * b.y + a.z * b.z + a.w * b.w;
                }
                float pw = bbpw[12 + lh];
                lg += ss + pw * (cr - 0.5f * (q2s_l[lq * 12 + lh] + k2s[kg * 12 + lh]));
                lg += 100000.0f * (mq_l[lq] * mk - 1.0f);
                lg *= sqrt3i;

                float tmax = lg;
#pragma unroll
                for (int off = 16; off >= 1; off >>= 1) tmax = fmaxf(tmax, __shfl_xor(tmax, off));
                float mold = m_l[qh];
                float mnew = fmaxf(mold, tmax);
                float p = __expf(lg - mnew);
                float tsum = p;
#pragma unroll
                for (int off = 16; off >= 1; off >>= 1) tsum += __shfl_xor(tsum, off);
                if (lg_kk == 0) {
                    float sc = __expf(mold - mnew);
                    sc_l_[qh] = sc;
                    l_l[qh] = l_l[qh] * sc + tsum;
                    m_l[qh] = mnew;
                }
                p_t[row * 16 + lh] = p;
            }
        }
        __syncthreads();

        // ---- accumulate ----
        {
            // o_pair: thread owns (q, c), 12 h accumulators
            const float* scp = &sc_l_[pr_q * 12];
#pragma unroll
            for (int h = 0; h < 12; ++h) a_pair[h] *= scp[h];
            const float* zb = &z_t[pr_q * TK * ZSTR + pr_c];
            const float* pb = &p_t[pr_q * TK * 16];
#pragma unroll 4
            for (int k = 0; k < TK; ++k) {
                float zv = zb[k * ZSTR];
                const float4* pp = (const float4*)(pb + k * 16);
                float4 p0 = pp[0], p1 = pp[1], p2 = pp[2];
                a_pair[0] += p0.x * zv; a_pair[1] += p0.y * zv; a_pair[2]  += p0.z * zv; a_pair[3]  += p0.w * zv;
                a_pair[4] += p1.x * zv; a_pair[5] += p1.y * zv; a_pair[6]  += p1.z * zv; a_pair[7]  += p1.w * zv;
                a_pair[8] += p2.x * zv; a_pair[9] += p2.y * zv; a_pair[10] += p2.z * zv; a_pair[11] += p2.w * zv;
            }
            // o / o_pt: thread owns one float4 of output
            if (ov_valid) {
                float sc = sc_l_[ov_q * 12 + ov_h];
                a_ov.x *= sc; a_ov.y *= sc; a_ov.z *= sc; a_ov.w *= sc;
                const float* pb2 = &p_t[ov_q * TK * 16 + ov_h];
                const float* src = ov_is_o ? (v_w + (size_t)k0 * 192 + ov_off)
                                           : (vp_w + (size_t)k0 * 288 + ov_off);
                const int sstr = ov_is_o ? 192 : 288;
#pragma unroll 4
                for (int k = 0; k < TK; ++k) {
                    float p = pb2[k * 16];
                    float4 v = *(const float4*)(src + (size_t)k * sstr);
                    a_ov.x += p * v.x; a_ov.y += p * v.y; a_ov.z += p * v.z; a_ov.w += p * v.w;
                }
            }
        }
    }

    // ---- epilogue ----
    {
        const float* lp = &l_l[pr_q * 12];
        float* cw = cat_w + (size_t)(q0 + pr_q) * 2112 + 576 + pr_c;
#pragma unroll
        for (int h = 0; h < 12; ++h) cw[h * 128] = a_pair[h] / lp[h];

        if (ov_is_o) {
            float rl = 1.0f / l_l[ov_q * 12 + ov_h];
            float* co = cat_w + (size_t)(q0 + ov_q) * 2112 + ov_off;
            co[0] = a_ov.x * rl; co[1] = a_ov.y * rl; co[2] = a_ov.z * rl; co[3] = a_ov.w * rl;
        } else if (ov_valid) {
            float rl = 1.0f / l_l[ov_q * 12 + ov_h];
            float* po = &opt_l[ov_q * 288 + ov_off];
            po[0] = a_ov.x * rl; po[1] = a_ov.y * rl; po[2] = a_ov.z * rl; po[3] = a_ov.w * rl;
        }
    }
    __syncthreads();
    if (t < 192) {   // o_pt: back to local frame + norm
        int q = t / 96, r = t % 96;
        int h = r >> 3, pp = r & 7;
        int n = q0 + q;
        const float* po = &opt_l[q * 288 + h * 24 + pp * 3];
        float x = po[0] - trans[n * 3 + 0];
        float y = po[1] - trans[n * 3 + 1];
        float zz = po[2] - trans[n * 3 + 2];
        const float* R = rot + n * 9;
        float lx = R[0] * x + R[3] * y + R[6] * zz;
        float ly = R[1] * x + R[4] * y + R[7] * zz;
        float lz = R[2] * x + R[5] * y + R[8] * zz;
        float* cw = cat_w + (size_t)n * 2112;
        int hp = h * 8 + pp;
        cw[192 + hp] = lx;
        cw[288 + hp] = ly;
        cw[384 + hp] = lz;
        cw[480 + hp] = sqrtf(lx * lx + ly * ly + lz * lz + 1e-8f);
    }
}

// ---------------------------------------------------------------------------
// K3: out = cat(768x2112) @ Wout(2112x384) + bout.  grid (96, 6), 256 thr.
// 8 rows x 64 cols per block; thread: 2 rows, float4 over contraction.
// ---------------------------------------------------------------------------
__global__ __launch_bounds__(256) void k3_out(
    const float* __restrict__ cat_w, const float* __restrict__ Wout,
    const float* __restrict__ bout, float* __restrict__ out)
{
    const int t = threadIdx.x;
    const int jl = t & 63, rh = t >> 6;
    const int j = blockIdx.y * 64 + jl;
    const int n0 = blockIdx.x * 8;
    const int r0 = rh * 2;
    const float* c0 = cat_w + (size_t)(n0 + r0) * 2112;
    const float* c1 = c0 + 2112;
    float a0 = 0.f, a1 = 0.f;
    for (int e4 = 0; e4 < 528; ++e4) {
        float4 x0 = *(const float4*)(c0 + e4 * 4);
        float4 x1 = *(const float4*)(c1 + e4 * 4);
        float w0 = Wout[(size_t)(e4 * 4 + 0) * 384 + j];
        float w1 = Wout[(size_t)(e4 * 4 + 1) * 384 + j];
        float w2 = Wout[(size_t)(e4 * 4 + 2) * 384 + j];
        float w3 = Wout[(size_t)(e4 * 4 + 3) * 384 + j];
        a0 += x0.x * w0 + x0.y * w1 + x0.z * w2 + x0.w * w3;
        a1 += x1.x * w0 + x1.y * w1 + x1.z * w2 + x1.w * w3;
    }
    float b = bout[j];
    out[(size_t)(n0 + r0) * 384 + j] = a0 + b;
    out[(size_t)(n0 + r0 + 1) * 384 + j] = a1 + b;
}

// ---------------------------------------------------------------------------
extern "C" void kernel_launch(void* const* d_in, const int* in_sizes, int n_in,
                              void* d_out, int out_size, void* d_ws, size_t ws_size,
                              hipStream_t stream)
{
    const float* s     = (const float*)d_in[0];
    const float* z     = (const float*)d_in[1];
    const float* rot   = (const float*)d_in[2];
    const float* trans = (const float*)d_in[3];
    const float* mask  = (const float*)d_in[4];
    const float* Wq    = (const float*)d_in[5];
    const float* Wk    = (const float*)d_in[6];
    const float* Wv    = (const float*)d_in[7];
    const float* Wqp   = (const float*)d_in[8];
    const float* bqp   = (const float*)d_in[9];
    const float* Wkp   = (const float*)d_in[10];
    const float* bkp   = (const float*)d_in[11];
    const float* Wvp   = (const float*)d_in[12];
    const float* bvp   = (const float*)d_in[13];
    const float* Wb    = (const float*)d_in[14];
    const float* bb    = (const float*)d_in[15];
    const float* hw    = (const float*)d_in[16];
    const float* Wout  = (const float*)d_in[17];
    const float* bout  = (const float*)d_in[18];
    float* out = (float*)d_out;

    // ws layout (floats): 10.1 MB total
    float* ws    = (float*)d_ws;
    float* qs_w  = ws;                 // 768*192
    float* ks_w  = ws + 147456;        // 768*192
    float* v_w   = ws + 294912;        // 768*192
    float* qp_w  = ws + 442368;        // 768*144
    float* kp_w  = ws + 552960;        // 768*144
    float* vp_w  = ws + 663552;        // 768*288
    float* q2s   = ws + 884736;        // 768*12
    float* k2s   = ws + 893952;        // 768*12
    float* cat_w = ws + 903168;        // 768*2112

    k1_proj<<<dim3(48, 9), 256, 0, stream>>>(s, Wq, Wk, Wv, Wqp, bqp, Wkp, bkp, Wvp, bvp,
                                             qs_w, ks_w, v_w, qp_w, kp_w, vp_w);
    k1b_points<<<dim3(36), 256, 0, stream>>>(rot, trans, qp_w, kp_w, vp_w, q2s, k2s);
    k2_attn<<<dim3(NN / TQ), 256, 0, stream>>>(z, mask, rot, trans, Wb, bb, hw,
                                               qs_w, ks_w, v_w, qp_w, kp_w, vp_w, q2s, k2s, cat_w);
    k3_out<<<dim3(96, 6), 256, 0, stream>>>(cat_w, Wout, bout, out);
}